// Round 4
// baseline (397.664 us; speedup 1.0000x reference)
//
#include <hip/hip_runtime.h>

// Local 5x5 window dot-product attention (fp32). B=2, H=W=256, C=BIN=32.
//   attn[p,k] = dot_c(main[p,:], ref[p+off_k,:])   (0 if OOB; zero-padded)
//   w = softmax_k(attn)   (no-max softmax is exact here: |s|<~30)
//   out[p,:]  = sum_k w[k] * ref_value[p+off_k,:]
//
// R4: vertical x4 register blocking. Each thread owns 4 vertically adjacent
// pixels (same column). Neighbor rows for the 4 outputs span 8 rows; each
// loaded (row, col-shift) line feeds up to 4 dot products. Loads drop from
// 50/pixel to 20/pixel -> ~330MB L1 traffic (was 819MB). That was the
// bottleneck (VMEM-throughput), VALU stays below the new VMEM floor.
//
// Wave layout: 8 pixel-columns x 8 lanes/column (one float4 = 4 channels).
// All wave-level loads/stores are contiguous 1KB segments. Score reduction
// across a pixel's 8 lanes: 3x shfl_xor (DPP). No LDS.

__global__ void __launch_bounds__(256, 4)
local_attn_kernel(const float* __restrict__ main_p,
                  const float* __restrict__ ref_p,
                  const float* __restrict__ rv_p,
                  float* __restrict__ out_p)
{
    const int lane = threadIdx.x & 63;
    const int wv   = threadIdx.x >> 6;
    const int cg   = lane & 7;          // float4 index within pixel (4 channels)
    const int pw   = lane >> 3;         // pixel-column within wave: 0..7

    // block tile: 32 wide x 4 tall. 1024 blocks total (B*H*W / 128).
    const int b     = blockIdx.x;
    const int batch = b >> 9;           // 512 tiles per image
    const int tb    = b & 511;
    const int ty    = tb >> 3;          // 0..63  -> h0 = ty*4
    const int tx    = tb & 7;           // 0..7   -> x0 = tx*32
    const int w0    = tx * 32 + wv * 8 + pw;
    const int h0    = ty * 4;
    const int bbase = batch << 16;      // batch * H*W

    const float4* m4 = (const float4*)main_p;
    const float4* r4 = (const float4*)ref_p;
    const float4* v4 = (const float4*)rv_p;
    float4*       o4 = (float4*)out_p;

    // main vectors for the 4 owned pixels
    float4 m0 = m4[(bbase + (h0 + 0) * 256 + w0) * 8 + cg];
    float4 m1 = m4[(bbase + (h0 + 1) * 256 + w0) * 8 + cg];
    float4 m2 = m4[(bbase + (h0 + 2) * 256 + w0) * 8 + cg];
    float4 m3 = m4[(bbase + (h0 + 3) * 256 + w0) * 8 + cg];

    // column shifts (per-lane)
    int   ccol[5];
    float cmask[5];
#pragma unroll
    for (int dj = 0; dj < 5; ++dj) {
        const int ww = w0 + dj - 2;
        cmask[dj] = ((unsigned)ww < 256u) ? 1.0f : 0.0f;
        ccol[dj]  = min(max(ww, 0), 255);
    }

    float  sum0 = 0.f, sum1 = 0.f, sum2 = 0.f, sum3 = 0.f;
    float4 a0 = make_float4(0.f,0.f,0.f,0.f), a1 = a0, a2 = a0, a3 = a0;

#pragma unroll
    for (int ri = 0; ri < 8; ++ri) {          // ref row = h0 + ri - 2
        const int   hh   = h0 + ri - 2;
        const float rok  = ((unsigned)hh < 256u) ? 1.0f : 0.0f;
        const int   rowb = bbase + min(max(hh, 0), 255) * 256;
#pragma unroll
        for (int dj = 0; dj < 5; ++dj) {
            const int   aoff = (rowb + ccol[dj]) * 8 + cg;
            const float msk  = rok * cmask[dj];
            const float4 r = r4[aoff];
            const float4 v = v4[aoff];
            // output rows t with t + di = ri, di in [0,4], t in [0,3]
#pragma unroll
            for (int t = (ri > 4 ? ri - 4 : 0); t <= (ri < 3 ? ri : 3); ++t) {
                const float4 mt = (t == 0) ? m0 : (t == 1) ? m1 : (t == 2) ? m2 : m3;
                float s = mt.x * r.x + mt.y * r.y + mt.z * r.z + mt.w * r.w;
                s += __shfl_xor(s, 1, 64);
                s += __shfl_xor(s, 2, 64);
                s += __shfl_xor(s, 4, 64);
                const float e  = __expf(s * msk);   // OOB -> exp(0)=1 (zero-pad)
                const float wk = e * msk;           // OOB value contributes 0
                if (t == 0) { sum0 += e; a0.x += wk*v.x; a0.y += wk*v.y; a0.z += wk*v.z; a0.w += wk*v.w; }
                if (t == 1) { sum1 += e; a1.x += wk*v.x; a1.y += wk*v.y; a1.z += wk*v.z; a1.w += wk*v.w; }
                if (t == 2) { sum2 += e; a2.x += wk*v.x; a2.y += wk*v.y; a2.z += wk*v.z; a2.w += wk*v.w; }
                if (t == 3) { sum3 += e; a3.x += wk*v.x; a3.y += wk*v.y; a3.z += wk*v.z; a3.w += wk*v.w; }
            }
        }
    }

    const float i0 = 1.0f / sum0, i1 = 1.0f / sum1, i2 = 1.0f / sum2, i3 = 1.0f / sum3;
    a0.x *= i0; a0.y *= i0; a0.z *= i0; a0.w *= i0;
    a1.x *= i1; a1.y *= i1; a1.z *= i1; a1.w *= i1;
    a2.x *= i2; a2.y *= i2; a2.z *= i2; a2.w *= i2;
    a3.x *= i3; a3.y *= i3; a3.z *= i3; a3.w *= i3;

    o4[(bbase + (h0 + 0) * 256 + w0) * 8 + cg] = a0;
    o4[(bbase + (h0 + 1) * 256 + w0) * 8 + cg] = a1;
    o4[(bbase + (h0 + 2) * 256 + w0) * 8 + cg] = a2;
    o4[(bbase + (h0 + 3) * 256 + w0) * 8 + cg] = a3;
}

extern "C" void kernel_launch(void* const* d_in, const int* in_sizes, int n_in,
                              void* d_out, int out_size, void* d_ws, size_t ws_size,
                              hipStream_t stream)
{
    const float* main_p = (const float*)d_in[0];
    const float* ref_p  = (const float*)d_in[1];
    const float* rv_p   = (const float*)d_in[2];
    float*       out_p  = (float*)d_out;

    const int npix   = in_sizes[0] / 32;   // B*H*W = 131072
    const int blocks = npix / 128;         // 128 pixels (32x4 tile) per block
    local_attn_kernel<<<blocks, 256, 0, stream>>>(main_p, ref_p, rv_p, out_p);
}

// Round 5
// 106.091 us; speedup vs baseline: 3.7483x; 3.7483x over previous
//
#include <hip/hip_runtime.h>

// Local 5x5 window dot-product attention (fp32). B=2, H=W=256, C=BIN=32.
//   attn[p,k] = dot_c(main[p,:], ref[p+off_k,:])   (0 if OOB; zero-padded)
//   w = softmax_k(attn)   (no-max softmax is exact: |s| <~ 30 for N(0,1) data)
//   out[p,:]  = sum_k w[k] * ref_value[p+off_k,:]
//
// R5: vertical x2 register blocking, fully static structure (R4 lesson: any
// variable-bound loop / indexed local array risks scratch demotion -> 630MB
// spill traffic). Each thread owns 2 vertically adjacent pixels; the 6
// neighbor rows x 5 col-shifts are loaded ONCE (r and v) and feed both
// outputs' dots. Wave VMEM ops: 64 per 16 pixels = 4.0/pixel vs R3's 6.5.
//
// Wave layout: 8 pixel-columns x 8 lanes/column (one float4 = 4 channels).
// All wave-level loads/stores are contiguous 1KB segments. Score reduction
// across a pixel's 8 lanes: 3x shfl_xor (DPP). No LDS, no arrays.

__global__ void __launch_bounds__(256)
local_attn_kernel(const float* __restrict__ main_p,
                  const float* __restrict__ ref_p,
                  const float* __restrict__ rv_p,
                  float* __restrict__ out_p)
{
    const int lane = threadIdx.x & 63;
    const int wv   = threadIdx.x >> 6;
    const int cg   = lane & 7;          // float4 index within pixel (4 channels)
    const int pw   = lane >> 3;         // pixel-column within wave: 0..7

    // grid: 2048 blocks; tile = 32 columns x 2 rows (1024 tiles per image)
    const int b     = blockIdx.x;
    const int batch = b >> 10;
    const int tb    = b & 1023;
    const int ty    = tb >> 3;          // 0..127 -> h0 = ty*2
    const int tx    = tb & 7;           // 0..7   -> col base = tx*32
    const int w0    = tx * 32 + wv * 8 + pw;
    const int h0    = ty * 2;
    const int bbase = batch << 16;      // batch * H*W

    const float4* m4 = (const float4*)main_p;
    const float4* r4 = (const float4*)ref_p;
    const float4* v4 = (const float4*)rv_p;
    float4*       o4 = (float4*)out_p;

    const float4 m0 = m4[(bbase + (h0 + 0) * 256 + w0) * 8 + cg];
    const float4 m1 = m4[(bbase + (h0 + 1) * 256 + w0) * 8 + cg];

    float  sum0 = 0.f, sum1 = 0.f;
    float4 a0 = make_float4(0.f, 0.f, 0.f, 0.f);
    float4 a1 = make_float4(0.f, 0.f, 0.f, 0.f);

#pragma unroll
    for (int ri = 0; ri < 6; ++ri) {          // neighbor row = h0 + ri - 2
        const int   hh   = h0 + ri - 2;
        const float rok  = ((unsigned)hh < 256u) ? 1.0f : 0.0f;
        const int   rowb = bbase + min(max(hh, 0), 255) * 256;
#pragma unroll
        for (int dj = 0; dj < 5; ++dj) {
            const int   ww  = w0 + dj - 2;
            const float msk = rok * (((unsigned)ww < 256u) ? 1.0f : 0.0f);
            const int   a   = (rowb + min(max(ww, 0), 255)) * 8 + cg;

            const float4 r = r4[a];
            const float4 v = v4[a];

            if (ri < 5) {   // contributes to output row h0 (row offset ri-2)
                float s = m0.x * r.x + m0.y * r.y + m0.z * r.z + m0.w * r.w;
                s += __shfl_xor(s, 1, 64);
                s += __shfl_xor(s, 2, 64);
                s += __shfl_xor(s, 4, 64);
                const float e  = __expf(s * msk);   // OOB -> exp(0)=1 (zero-pad)
                const float wk = e * msk;
                sum0 += e;
                a0.x += wk * v.x; a0.y += wk * v.y;
                a0.z += wk * v.z; a0.w += wk * v.w;
            }
            if (ri >= 1) {  // contributes to output row h0+1 (row offset ri-3)
                float s = m1.x * r.x + m1.y * r.y + m1.z * r.z + m1.w * r.w;
                s += __shfl_xor(s, 1, 64);
                s += __shfl_xor(s, 2, 64);
                s += __shfl_xor(s, 4, 64);
                const float e  = __expf(s * msk);
                const float wk = e * msk;
                sum1 += e;
                a1.x += wk * v.x; a1.y += wk * v.y;
                a1.z += wk * v.z; a1.w += wk * v.w;
            }
        }
    }

    const float i0 = 1.0f / sum0;
    const float i1 = 1.0f / sum1;
    a0.x *= i0; a0.y *= i0; a0.z *= i0; a0.w *= i0;
    a1.x *= i1; a1.y *= i1; a1.z *= i1; a1.w *= i1;

    o4[(bbase + (h0 + 0) * 256 + w0) * 8 + cg] = a0;
    o4[(bbase + (h0 + 1) * 256 + w0) * 8 + cg] = a1;
}

extern "C" void kernel_launch(void* const* d_in, const int* in_sizes, int n_in,
                              void* d_out, int out_size, void* d_ws, size_t ws_size,
                              hipStream_t stream)
{
    const float* main_p = (const float*)d_in[0];
    const float* ref_p  = (const float*)d_in[1];
    const float* rv_p   = (const float*)d_in[2];
    float*       out_p  = (float*)d_out;

    const int npix   = in_sizes[0] / 32;   // B*H*W = 131072
    const int blocks = npix / 64;          // 64 pixels (32x2 tile) per block
    local_attn_kernel<<<blocks, 256, 0, stream>>>(main_p, ref_p, rv_p, out_p);
}